// Round 1
// baseline (502.779 us; speedup 1.0000x reference)
//
#include <hip/hip_runtime.h>
#include <hip/hip_bf16.h>
#include <stdint.h>

#define T_DIM 4096
#define H_DIM 1024
#define I_DIM 1024
#define E_DIM 8
#define F_DIM 2048          // 2*I
#define K2_DIM 8192         // E*I
#define ALPHA_C 1.702f
#define LIMIT_C 7.0f

typedef unsigned short u16;
typedef __bf16 bf8 __attribute__((ext_vector_type(8)));
typedef float f4 __attribute__((ext_vector_type(4)));

__device__ __forceinline__ u16 f2bf(float f) {
  union { float f; unsigned u; } x; x.f = f;
  unsigned r = (x.u + 0x7fffu + ((x.u >> 16) & 1u)) >> 16;
  return (u16)r;
}

__device__ __forceinline__ void gload16(const void* g, void* l) {
  __builtin_amdgcn_global_load_lds(
      (const __attribute__((address_space(1))) void*)g,
      (__attribute__((address_space(3))) void*)l,
      16, 0, 0);
}

// ---------------- cast kernels ----------------

__global__ void cast_bf16_kernel(const float* __restrict__ in, u16* __restrict__ out, int n4) {
  int idx = blockIdx.x * blockDim.x + threadIdx.x;
  int stride = gridDim.x * blockDim.x;
  for (int i = idx; i < n4; i += stride) {
    float4 v = reinterpret_cast<const float4*>(in)[i];
    ushort4 o;
    o.x = f2bf(v.x); o.y = f2bf(v.y); o.z = f2bf(v.z); o.w = f2bf(v.w);
    reinterpret_cast<ushort4*>(out)[i] = o;
  }
}

// gate_up_proj (E,H,F) f32 -> (E,F,H) bf16
__global__ void cast_transpose_gup(const float* __restrict__ in, u16* __restrict__ out) {
  __shared__ float tile[32][33];
  int e = blockIdx.z, h0 = blockIdx.y * 32, f0 = blockIdx.x * 32;
  int tx = threadIdx.x & 31, ty = threadIdx.x >> 5;  // 32 x 8
  const float* src = in + (size_t)e * H_DIM * F_DIM;
  u16* dst = out + (size_t)e * F_DIM * H_DIM;
#pragma unroll
  for (int r = ty; r < 32; r += 8) tile[r][tx] = src[(size_t)(h0 + r) * F_DIM + f0 + tx];
  __syncthreads();
#pragma unroll
  for (int r = ty; r < 32; r += 8) dst[(size_t)(f0 + r) * H_DIM + h0 + tx] = f2bf(tile[tx][r]);
}

// ---------------- GEMM1: hs(T,H) x gupT(E,F,H)^T -> act2(T, E*I) with fused bias+act+rw ----------------

__global__ __launch_bounds__(256, 2) void gemm1_act(
    const u16* __restrict__ A,      // hs_bf (T,H)
    const u16* __restrict__ Bt,     // gupT (E,F,H)
    const float* __restrict__ rw,   // (T,E)
    const float* __restrict__ gbias,// (E,F)
    u16* __restrict__ act2)         // (T, E*I)
{
  const int e  = blockIdx.z;
  const int t0 = blockIdx.y * 128;
  const int n0 = blockIdx.x * 128;
  const int tid = threadIdx.x;
  const int w = tid >> 6, l = tid & 63;
  const int wr = w >> 1, wc = w & 1;

  __shared__ u16 As[128 * 32];
  __shared__ u16 Bs[128 * 32];
  __shared__ float rw_s[128];
  __shared__ float gb_s[128];

  if (tid < 128) {
    rw_s[tid] = rw[(size_t)(t0 + tid) * E_DIM + e];
    gb_s[tid] = gbias[(size_t)e * F_DIM + n0 + tid];
  }

  const u16* bBase = Bt + (size_t)e * F_DIM * H_DIM;

  f4 acc[4][4];
#pragma unroll
  for (int m = 0; m < 4; ++m)
#pragma unroll
    for (int n = 0; n < 4; ++n) acc[m][n] = f4{0.f, 0.f, 0.f, 0.f};

  const int row_st = l >> 2;          // 0..15
  const int col_st = (l & 3) * 8;     // 0,8,16,24

  for (int kt = 0; kt < H_DIM / 32; ++kt) {
    const int k0 = kt * 32;
    __syncthreads();   // previous iter's frags consumed
#pragma unroll
    for (int c = 0; c < 2; ++c) {
      int q = w * 2 + c;                 // 0..7 -> rows [16q,16q+16)
      int row = q * 16 + row_st;
      gload16(A + (size_t)(t0 + row) * H_DIM + k0 + col_st, (char*)As + q * 1024);
      gload16(bBase + (size_t)(n0 + row) * H_DIM + k0 + col_st, (char*)Bs + q * 1024);
    }
    __syncthreads();   // staging complete (vmcnt drained by barrier)

    bf8 af[4], bfr[4];
#pragma unroll
    for (int m = 0; m < 4; ++m) {
      int row = wr * 64 + m * 16 + (l & 15);
      af[m] = *(const bf8*)(As + row * 32 + (l >> 4) * 8);
    }
#pragma unroll
    for (int n = 0; n < 4; ++n) {
      int row = wc * 64 + n * 16 + (l & 15);
      bfr[n] = *(const bf8*)(Bs + row * 32 + (l >> 4) * 8);
    }
#pragma unroll
    for (int m = 0; m < 4; ++m)
#pragma unroll
      for (int n = 0; n < 4; ++n)
        acc[m][n] = __builtin_amdgcn_mfma_f32_16x16x32_bf16(af[m], bfr[n], acc[m][n], 0, 0, 0);
  }

  // epilogue: bias, pair gate/up via shfl, activation, scale by rw, store bf16
#pragma unroll
  for (int m = 0; m < 4; ++m) {
#pragma unroll
    for (int n = 0; n < 4; ++n) {
#pragma unroll
      for (int r = 0; r < 4; ++r) {
        int row = wr * 64 + m * 16 + (l >> 4) * 4 + r;
        int col = wc * 64 + n * 16 + (l & 15);
        float v = acc[m][n][r] + gb_s[col];
        float o = __shfl_xor(v, 1, 64);
        float gate = (l & 1) ? o : v;
        float up   = (l & 1) ? v : o;
        gate = fminf(gate, LIMIT_C);
        up   = fminf(fmaxf(up, -LIMIT_C), LIMIT_C);
        float glu = gate / (1.f + __expf(-gate * ALPHA_C));
        float a = (up + 1.f) * glu * rw_s[row];
        if (!(l & 1)) {
          int i = (n0 + col) >> 1;
          act2[(size_t)(t0 + row) * K2_DIM + e * I_DIM + i] = f2bf(a);
        }
      }
    }
  }
}

// ---------------- GEMM2: act2(T,8192) x dp_bf(E,H,I) -> out(T,H) with fused routed down-bias ----------------

__global__ __launch_bounds__(256, 2) void gemm2(
    const u16* __restrict__ A,      // act2 (T, 8192)
    const u16* __restrict__ Bt,     // dp_bf (E,H,I)
    const float* __restrict__ rw,   // (T,E)
    const float* __restrict__ dbias,// (E,I)
    float* __restrict__ out)        // (T,H)
{
  const int t0 = blockIdx.y * 128;
  const int n0 = blockIdx.x * 128;   // h
  const int tid = threadIdx.x;
  const int w = tid >> 6, l = tid & 63;
  const int wr = w >> 1, wc = w & 1;

  __shared__ u16 As[128 * 32];
  __shared__ u16 Bs[128 * 32];
  __shared__ float rw_s[128 * 8];   // [t][e]
  __shared__ float db_s[8 * 128];   // [e][c]

  {
    reinterpret_cast<float4*>(rw_s)[tid] =
        reinterpret_cast<const float4*>(rw + (size_t)t0 * E_DIM)[tid];
    int idx0 = tid * 4;
    int ee = idx0 >> 7, c = idx0 & 127;
    reinterpret_cast<float4*>(db_s)[tid] =
        *reinterpret_cast<const float4*>(dbias + (size_t)ee * I_DIM + n0 + c);
  }

  f4 acc[4][4];
#pragma unroll
  for (int m = 0; m < 4; ++m)
#pragma unroll
    for (int n = 0; n < 4; ++n) acc[m][n] = f4{0.f, 0.f, 0.f, 0.f};

  const int row_st = l >> 2;
  const int col_st = (l & 3) * 8;

  for (int kt = 0; kt < K2_DIM / 32; ++kt) {
    const int k0 = kt * 32;
    const int eb = k0 >> 10;
    const int ki = k0 & 1023;
    __syncthreads();
#pragma unroll
    for (int c = 0; c < 2; ++c) {
      int q = w * 2 + c;
      int row = q * 16 + row_st;
      gload16(A + (size_t)(t0 + row) * K2_DIM + k0 + col_st, (char*)As + q * 1024);
      gload16(Bt + ((size_t)eb * H_DIM + n0 + row) * I_DIM + ki + col_st, (char*)Bs + q * 1024);
    }
    __syncthreads();

    bf8 af[4], bfr[4];
#pragma unroll
    for (int m = 0; m < 4; ++m) {
      int row = wr * 64 + m * 16 + (l & 15);
      af[m] = *(const bf8*)(As + row * 32 + (l >> 4) * 8);
    }
#pragma unroll
    for (int n = 0; n < 4; ++n) {
      int row = wc * 64 + n * 16 + (l & 15);
      bfr[n] = *(const bf8*)(Bs + row * 32 + (l >> 4) * 8);
    }
#pragma unroll
    for (int m = 0; m < 4; ++m)
#pragma unroll
      for (int n = 0; n < 4; ++n)
        acc[m][n] = __builtin_amdgcn_mfma_f32_16x16x32_bf16(af[m], bfr[n], acc[m][n], 0, 0, 0);
  }

#pragma unroll
  for (int m = 0; m < 4; ++m) {
#pragma unroll
    for (int n = 0; n < 4; ++n) {
#pragma unroll
      for (int r = 0; r < 4; ++r) {
        int row = wr * 64 + m * 16 + (l >> 4) * 4 + r;
        int col = wc * 64 + n * 16 + (l & 15);
        float rb = 0.f;
#pragma unroll
        for (int ee = 0; ee < 8; ++ee) rb += rw_s[row * 8 + ee] * db_s[ee * 128 + col];
        out[(size_t)(t0 + row) * H_DIM + n0 + col] = acc[m][n][r] + rb;
      }
    }
  }
}

// ---------------- launch ----------------

extern "C" void kernel_launch(void* const* d_in, const int* in_sizes, int n_in,
                              void* d_out, int out_size, void* d_ws, size_t ws_size,
                              hipStream_t stream) {
  const float* hs  = (const float*)d_in[0];
  const float* rw  = (const float*)d_in[1];
  const float* gup = (const float*)d_in[2];
  const float* gub = (const float*)d_in[3];
  const float* dp  = (const float*)d_in[4];
  const float* db  = (const float*)d_in[5];
  float* out = (float*)d_out;
  char* ws = (char*)d_ws;

  u16* hs_bf = (u16*)(ws);                          //  8 MiB (T*H*2)
  u16* gupT  = (u16*)(ws + 8ll  * 1024 * 1024);     // 32 MiB (E*F*H*2)
  u16* dp_bf = (u16*)(ws + 40ll * 1024 * 1024);     // 16 MiB (E*H*I*2)
  u16* act2  = (u16*)(ws + 56ll * 1024 * 1024);     // 64 MiB (T*E*I*2)

  cast_bf16_kernel<<<2048, 256, 0, stream>>>(hs, hs_bf, T_DIM * H_DIM / 4);
  cast_transpose_gup<<<dim3(F_DIM / 32, H_DIM / 32, E_DIM), 256, 0, stream>>>(gup, gupT);
  cast_bf16_kernel<<<2048, 256, 0, stream>>>(dp, dp_bf, E_DIM * H_DIM * I_DIM / 4);
  gemm1_act<<<dim3(F_DIM / 128, T_DIM / 128, E_DIM), 256, 0, stream>>>(hs_bf, gupT, rw, gub, act2);
  gemm2<<<dim3(H_DIM / 128, T_DIM / 128), 256, 0, stream>>>(act2, dp_bf, rw, db, out);
}

// Round 3
// 491.869 us; speedup vs baseline: 1.0222x; 1.0222x over previous
//
#include <hip/hip_runtime.h>
#include <hip/hip_bf16.h>
#include <stdint.h>

#define T_DIM 4096
#define H_DIM 1024
#define I_DIM 1024
#define E_DIM 8
#define F_DIM 2048          // 2*I
#define K2_DIM 8192         // E*I
#define ALPHA_C 1.702f
#define LIMIT_C 7.0f

typedef unsigned short u16;
typedef __bf16 bf8 __attribute__((ext_vector_type(8)));
typedef float f4 __attribute__((ext_vector_type(4)));

__device__ __forceinline__ u16 f2bf(float f) {
  union { float f; unsigned u; } x; x.f = f;
  unsigned r = (x.u + 0x7fffu + ((x.u >> 16) & 1u)) >> 16;
  return (u16)r;
}

__device__ __forceinline__ void gload16(const void* g, void* l) {
  __builtin_amdgcn_global_load_lds(
      (const __attribute__((address_space(1))) void*)g,
      (__attribute__((address_space(3))) void*)l,
      16, 0, 0);
}

// ---------------- cast kernels ----------------

__global__ void cast_bf16_kernel(const float* __restrict__ in, u16* __restrict__ out, int n4) {
  int idx = blockIdx.x * blockDim.x + threadIdx.x;
  int stride = gridDim.x * blockDim.x;
  for (int i = idx; i < n4; i += stride) {
    float4 v = reinterpret_cast<const float4*>(in)[i];
    ushort4 o;
    o.x = f2bf(v.x); o.y = f2bf(v.y); o.z = f2bf(v.z); o.w = f2bf(v.w);
    reinterpret_cast<ushort4*>(out)[i] = o;
  }
}

// gate_up_proj (E,H,F) f32 -> (E,F,H) bf16
__global__ void cast_transpose_gup(const float* __restrict__ in, u16* __restrict__ out) {
  __shared__ float tile[32][33];
  int e = blockIdx.z, h0 = blockIdx.y * 32, f0 = blockIdx.x * 32;
  int tx = threadIdx.x & 31, ty = threadIdx.x >> 5;  // 32 x 8
  const float* src = in + (size_t)e * H_DIM * F_DIM;
  u16* dst = out + (size_t)e * F_DIM * H_DIM;
#pragma unroll
  for (int r = ty; r < 32; r += 8) tile[r][tx] = src[(size_t)(h0 + r) * F_DIM + f0 + tx];
  __syncthreads();
#pragma unroll
  for (int r = ty; r < 32; r += 8) dst[(size_t)(f0 + r) * H_DIM + h0 + tx] = f2bf(tile[tx][r]);
}

// out[t,h] = sum_e rw[t,e]*db[e,h]  (routed down-bias init; gemm2 atomicAdds on top)
__global__ void bias_init(const float* __restrict__ rw, const float* __restrict__ db,
                          float* __restrict__ out) {
  __shared__ float db_s[E_DIM][H_DIM];
  for (int i = threadIdx.x; i < E_DIM * H_DIM; i += 256)
    db_s[i >> 10][i & 1023] = db[i];
  int t = blockIdx.x;
  float r0[E_DIM];
#pragma unroll
  for (int e = 0; e < E_DIM; ++e) r0[e] = rw[(size_t)t * E_DIM + e];
  __syncthreads();
  for (int h = threadIdx.x; h < H_DIM; h += 256) {
    float s = 0.f;
#pragma unroll
    for (int e = 0; e < E_DIM; ++e) s += r0[e] * db_s[e][h];
    out[(size_t)t * H_DIM + h] = s;
  }
}

// ---------------- GEMM1: hs(T,H) x gupT(E,F,H)^T -> act2(T, E*I) fused bias+act+rw ----------------

__global__ __launch_bounds__(256, 2) void gemm1_act(
    const u16* __restrict__ A,      // hs_bf (T,H)
    const u16* __restrict__ Bt,     // gupT (E,F,H)
    const float* __restrict__ rw,   // (T,E)
    const float* __restrict__ gbias,// (E,F)
    u16* __restrict__ act2)         // (T, E*I)
{
  const int e  = blockIdx.z;
  const int t0 = blockIdx.y * 128;
  const int n0 = blockIdx.x * 128;
  const int tid = threadIdx.x;
  const int w = tid >> 6, l = tid & 63;
  const int wr = w >> 1, wc = w & 1;

  __shared__ u16 As[128 * 32];
  __shared__ u16 Bs[128 * 32];
  __shared__ float rw_s[128];
  __shared__ float gb_s[128];

  if (tid < 128) {
    rw_s[tid] = rw[(size_t)(t0 + tid) * E_DIM + e];
    gb_s[tid] = gbias[(size_t)e * F_DIM + n0 + tid];
  }

  const u16* bBase = Bt + (size_t)e * F_DIM * H_DIM;

  f4 acc[4][4];
#pragma unroll
  for (int m = 0; m < 4; ++m)
#pragma unroll
    for (int n = 0; n < 4; ++n) acc[m][n] = f4{0.f, 0.f, 0.f, 0.f};

  // staging: lane l -> LDS linear slot l*16B = (row=l>>2, chunk=l&3).
  // Swizzled layout: LDS (row, c) holds global chunk c ^ ((row>>1)&3).
  const int row_st = l >> 2;                          // 0..15
  const int col_sw = (((l & 3) ^ ((l >> 3) & 3)) * 8); // XOR-permuted global chunk

  for (int kt = 0; kt < H_DIM / 32; ++kt) {
    const int k0 = kt * 32;
    __syncthreads();
#pragma unroll
    for (int c = 0; c < 2; ++c) {
      int q = w * 2 + c;                 // 0..7 -> rows [16q,16q+16)
      int row = q * 16 + row_st;
      gload16(A + (size_t)(t0 + row) * H_DIM + k0 + col_sw, (char*)As + q * 1024);
      gload16(bBase + (size_t)(n0 + row) * H_DIM + k0 + col_sw, (char*)Bs + q * 1024);
    }
    __syncthreads();

    bf8 af[4], bfr[4];
#pragma unroll
    for (int m = 0; m < 4; ++m) {
      int row = wr * 64 + m * 16 + (l & 15);
      int ch = (l >> 4) ^ ((row >> 1) & 3);
      af[m] = *(const bf8*)(As + row * 32 + ch * 8);
    }
#pragma unroll
    for (int n = 0; n < 4; ++n) {
      int row = wc * 64 + n * 16 + (l & 15);
      int ch = (l >> 4) ^ ((row >> 1) & 3);
      bfr[n] = *(const bf8*)(Bs + row * 32 + ch * 8);
    }
#pragma unroll
    for (int m = 0; m < 4; ++m)
#pragma unroll
      for (int n = 0; n < 4; ++n)
        acc[m][n] = __builtin_amdgcn_mfma_f32_16x16x32_bf16(af[m], bfr[n], acc[m][n], 0, 0, 0);
  }

  // epilogue: bias, pair gate/up via shfl, activation, scale by rw, store bf16
#pragma unroll
  for (int m = 0; m < 4; ++m) {
#pragma unroll
    for (int n = 0; n < 4; ++n) {
#pragma unroll
      for (int r = 0; r < 4; ++r) {
        int row = wr * 64 + m * 16 + (l >> 4) * 4 + r;
        int col = wc * 64 + n * 16 + (l & 15);
        float v = acc[m][n][r] + gb_s[col];
        float o = __shfl_xor(v, 1, 64);
        float gate = (l & 1) ? o : v;
        float up   = (l & 1) ? v : o;
        gate = fminf(gate, LIMIT_C);
        up   = fminf(fmaxf(up, -LIMIT_C), LIMIT_C);
        float glu = gate / (1.f + __expf(-gate * ALPHA_C));
        float a = (up + 1.f) * glu * rw_s[row];
        if (!(l & 1)) {
          int i = (n0 + col) >> 1;
          act2[(size_t)(t0 + row) * K2_DIM + e * I_DIM + i] = f2bf(a);
        }
      }
    }
  }
}

// ---------------- GEMM2: act2(T,8192) x dp_bf(E,H,I) -> atomicAdd out(T,H), split-K ----------------

__global__ __launch_bounds__(256, 2) void gemm2(
    const u16* __restrict__ A,      // act2 (T, 8192)
    const u16* __restrict__ Bt,     // dp_bf (E,H,I)
    float* __restrict__ out)        // (T,H), pre-initialized with routed bias
{
  const int t0 = blockIdx.y * 128;
  const int n0 = blockIdx.x * 128;   // h
  const int s  = blockIdx.z;         // split-K index, 4 splits of 64 kt each
  const int tid = threadIdx.x;
  const int w = tid >> 6, l = tid & 63;
  const int wr = w >> 1, wc = w & 1;

  __shared__ u16 As[128 * 32];
  __shared__ u16 Bs[128 * 32];

  f4 acc[4][4];
#pragma unroll
  for (int m = 0; m < 4; ++m)
#pragma unroll
    for (int n = 0; n < 4; ++n) acc[m][n] = f4{0.f, 0.f, 0.f, 0.f};

  const int row_st = l >> 2;
  const int col_sw = (((l & 3) ^ ((l >> 3) & 3)) * 8);

  const int kt_beg = s * (K2_DIM / 32 / 4);
  const int kt_end = kt_beg + (K2_DIM / 32 / 4);
  for (int kt = kt_beg; kt < kt_end; ++kt) {
    const int k0 = kt * 32;
    const int eb = k0 >> 10;
    const int ki = k0 & 1023;
    __syncthreads();
#pragma unroll
    for (int c = 0; c < 2; ++c) {
      int q = w * 2 + c;
      int row = q * 16 + row_st;
      gload16(A + (size_t)(t0 + row) * K2_DIM + k0 + col_sw, (char*)As + q * 1024);
      gload16(Bt + ((size_t)eb * H_DIM + n0 + row) * I_DIM + ki + col_sw, (char*)Bs + q * 1024);
    }
    __syncthreads();

    bf8 af[4], bfr[4];
#pragma unroll
    for (int m = 0; m < 4; ++m) {
      int row = wr * 64 + m * 16 + (l & 15);
      int ch = (l >> 4) ^ ((row >> 1) & 3);
      af[m] = *(const bf8*)(As + row * 32 + ch * 8);
    }
#pragma unroll
    for (int n = 0; n < 4; ++n) {
      int row = wc * 64 + n * 16 + (l & 15);
      int ch = (l >> 4) ^ ((row >> 1) & 3);
      bfr[n] = *(const bf8*)(Bs + row * 32 + ch * 8);
    }
#pragma unroll
    for (int m = 0; m < 4; ++m)
#pragma unroll
      for (int n = 0; n < 4; ++n)
        acc[m][n] = __builtin_amdgcn_mfma_f32_16x16x32_bf16(af[m], bfr[n], acc[m][n], 0, 0, 0);
  }

#pragma unroll
  for (int m = 0; m < 4; ++m) {
#pragma unroll
    for (int n = 0; n < 4; ++n) {
#pragma unroll
      for (int r = 0; r < 4; ++r) {
        int row = wr * 64 + m * 16 + (l >> 4) * 4 + r;
        int col = wc * 64 + n * 16 + (l & 15);
        atomicAdd(out + (size_t)(t0 + row) * H_DIM + n0 + col, acc[m][n][r]);
      }
    }
  }
}

// ---------------- launch ----------------

extern "C" void kernel_launch(void* const* d_in, const int* in_sizes, int n_in,
                              void* d_out, int out_size, void* d_ws, size_t ws_size,
                              hipStream_t stream) {
  const float* hs  = (const float*)d_in[0];
  const float* rw  = (const float*)d_in[1];
  const float* gup = (const float*)d_in[2];
  const float* gub = (const float*)d_in[3];
  const float* dp  = (const float*)d_in[4];
  const float* db  = (const float*)d_in[5];
  float* out = (float*)d_out;
  char* ws = (char*)d_ws;

  u16* hs_bf = (u16*)(ws);                          //  8 MiB (T*H*2)
  u16* gupT  = (u16*)(ws + 8ll  * 1024 * 1024);     // 32 MiB (E*F*H*2)
  u16* dp_bf = (u16*)(ws + 40ll * 1024 * 1024);     // 16 MiB (E*H*I*2)
  u16* act2  = (u16*)(ws + 56ll * 1024 * 1024);     // 64 MiB (T*E*I*2)

  cast_bf16_kernel<<<2048, 256, 0, stream>>>(hs, hs_bf, T_DIM * H_DIM / 4);
  cast_transpose_gup<<<dim3(F_DIM / 32, H_DIM / 32, E_DIM), 256, 0, stream>>>(gup, gupT);
  cast_bf16_kernel<<<2048, 256, 0, stream>>>(dp, dp_bf, E_DIM * H_DIM * I_DIM / 4);
  bias_init<<<T_DIM, 256, 0, stream>>>(rw, db, out);
  gemm1_act<<<dim3(F_DIM / 128, T_DIM / 128, E_DIM), 256, 0, stream>>>(hs_bf, gupT, rw, gub, act2);
  gemm2<<<dim3(H_DIM / 128, T_DIM / 128, 4), 256, 0, stream>>>(act2, dp_bf, out);
}

// Round 4
// 466.933 us; speedup vs baseline: 1.0768x; 1.0534x over previous
//
#include <hip/hip_runtime.h>
#include <hip/hip_bf16.h>
#include <stdint.h>

#define T_DIM 4096
#define H_DIM 1024
#define I_DIM 1024
#define E_DIM 8
#define F_DIM 2048          // 2*I
#define K2_DIM 8192         // E*I
#define ALPHA_C 1.702f
#define LIMIT_C 7.0f

typedef unsigned short u16;
typedef __bf16 bf8 __attribute__((ext_vector_type(8)));
typedef float f4 __attribute__((ext_vector_type(4)));

#define MFMA16(d, va, vb) d = __builtin_amdgcn_mfma_f32_16x16x32_bf16(va, vb, d, 0, 0, 0)
#define VMW(n) asm volatile("s_waitcnt vmcnt(" #n ")" ::: "memory")
#define LGKM0 asm volatile("s_waitcnt lgkmcnt(0)" ::: "memory")
#define SBAR __builtin_amdgcn_s_barrier()
#define SCHED0 __builtin_amdgcn_sched_barrier(0)

__device__ __forceinline__ u16 f2bf(float f) {
  union { float f; unsigned u; } x; x.f = f;
  unsigned r = (x.u + 0x7fffu + ((x.u >> 16) & 1u)) >> 16;
  return (u16)r;
}

__device__ __forceinline__ void gload16(const void* g, void* l) {
  __builtin_amdgcn_global_load_lds(
      (const __attribute__((address_space(1))) void*)g,
      (__attribute__((address_space(3))) void*)l,
      16, 0, 0);
}

// ---------------- cast kernels ----------------

__global__ void cast_bf16_kernel(const float* __restrict__ in, u16* __restrict__ out, int n4) {
  int idx = blockIdx.x * blockDim.x + threadIdx.x;
  int stride = gridDim.x * blockDim.x;
  for (int i = idx; i < n4; i += stride) {
    float4 v = reinterpret_cast<const float4*>(in)[i];
    ushort4 o;
    o.x = f2bf(v.x); o.y = f2bf(v.y); o.z = f2bf(v.z); o.w = f2bf(v.w);
    reinterpret_cast<ushort4*>(out)[i] = o;
  }
}

// gate_up_proj (E,H,F) f32 -> (E,F,H) bf16
__global__ void cast_transpose_gup(const float* __restrict__ in, u16* __restrict__ out) {
  __shared__ float tile[32][33];
  int e = blockIdx.z, h0 = blockIdx.y * 32, f0 = blockIdx.x * 32;
  int tx = threadIdx.x & 31, ty = threadIdx.x >> 5;  // 32 x 8
  const float* src = in + (size_t)e * H_DIM * F_DIM;
  u16* dst = out + (size_t)e * F_DIM * H_DIM;
#pragma unroll
  for (int r = ty; r < 32; r += 8) tile[r][tx] = src[(size_t)(h0 + r) * F_DIM + f0 + tx];
  __syncthreads();
#pragma unroll
  for (int r = ty; r < 32; r += 8) dst[(size_t)(f0 + r) * H_DIM + h0 + tx] = f2bf(tile[tx][r]);
}

// out[t,h] = sum_e rw[t,e]*db[e,h]  (routed down-bias init; gemm2 atomicAdds on top)
__global__ void bias_init(const float* __restrict__ rw, const float* __restrict__ db,
                          float* __restrict__ out) {
  __shared__ float db_s[E_DIM][H_DIM];
  for (int i = threadIdx.x; i < E_DIM * H_DIM; i += 256)
    db_s[i >> 10][i & 1023] = db[i];
  int t = blockIdx.x;
  float r0[E_DIM];
#pragma unroll
  for (int e = 0; e < E_DIM; ++e) r0[e] = rw[(size_t)t * E_DIM + e];
  __syncthreads();
  for (int h = threadIdx.x; h < H_DIM; h += 256) {
    float s = 0.f;
#pragma unroll
    for (int e = 0; e < E_DIM; ++e) s += r0[e] * db_s[e][h];
    out[(size_t)t * H_DIM + h] = s;
  }
}

// ============ GEMM1: 256x256 tile, BK=64, 8 waves, 4-phase pipelined ============
// hs(T,H) x gupT(E,F,H)^T -> act2(T,E*I), fused bias + clipped-SiLU-GLU + rw.

__global__ __launch_bounds__(512, 2) void gemm1_act8(
    const u16* __restrict__ A,      // hs_bf (T,H)
    const u16* __restrict__ Bt,     // gupT (E,F,H)
    const float* __restrict__ rw,   // (T,E)
    const float* __restrict__ gbias,// (E,F)
    u16* __restrict__ act2)         // (T, E*I)
{
  __shared__ __align__(16) u16 ldsbuf[65536];   // 128 KiB: [2 buf][A 16384 | B 16384]
  const int e  = blockIdx.z;
  const int t0 = blockIdx.y * 256;
  const int n0 = blockIdx.x * 256;
  const int tid = threadIdx.x;
  const int l = tid & 63, w = tid >> 6;
  const int wm = w >> 2, wn = w & 3;

  // stage addressing: thread covers row g, 16B chunk cl (source chunk XOR-swizzled)
  const int g = tid >> 3, cl = tid & 7;
  int ra[4] = { g, 128 + g, 64 + g, 192 + g };                 // ph1a,ph1b,ph4a,ph4b
  int rbb = (g & 31) + ((g >> 5) << 6);
  int rb[4] = { rbb, 128 + rbb, 32 + rbb, 160 + rbb };          // ph2a,ph2b,ph3a,ph3b
  const u16* gA[4]; const u16* gB[4]; int dA[4], dB[4];
  const u16* bB = Bt + (size_t)e * F_DIM * H_DIM;
#pragma unroll
  for (int j = 0; j < 4; ++j) {
    gA[j] = A + (size_t)(t0 + ra[j]) * H_DIM + (cl ^ ((ra[j] >> 1) & 7)) * 8;
    dA[j] = ra[j] * 64 + cl * 8;
    gB[j] = bB + (size_t)(n0 + rb[j]) * H_DIM + (cl ^ ((rb[j] >> 1) & 7)) * 8;
    dB[j] = 16384 + rb[j] * 64 + cl * 8;
  }

  // ds_read fragment addressing (swizzle reduces to lane-only term)
  const int lr = l & 15, qq = l >> 4, sw = (l >> 1) & 7;
  const int ks0 = (qq ^ sw) * 8, ks1 = ((4 + qq) ^ sw) * 8;
  const int aRow = (wm * 128 + lr) * 64;
  const int bRow = 16384 + (wn * 64 + lr) * 64;

  f4 acc[8][4];
#pragma unroll
  for (int i = 0; i < 8; ++i)
#pragma unroll
    for (int j = 0; j < 4; ++j) acc[i][j] = f4{0.f, 0.f, 0.f, 0.f};

  // prologue: stage tile 0 into buf0 in consumption order
  gload16(gA[0], ldsbuf + dA[0]); gload16(gA[1], ldsbuf + dA[1]);
  gload16(gB[0], ldsbuf + dB[0]); gload16(gB[1], ldsbuf + dB[1]);
  gload16(gB[2], ldsbuf + dB[2]); gload16(gB[3], ldsbuf + dB[3]);
  gload16(gA[2], ldsbuf + dA[2]); gload16(gA[3], ldsbuf + dA[3]);
  VMW(4);
  SBAR;

  bf8 af[4][2], b0[2][2], b1[2][2];
  const int NT = H_DIM / 64;   // 16
  for (int t = 0; t < NT; ++t) {
    const u16* L = ldsbuf + (t & 1) * 32768;
    u16* S = ldsbuf + ((t + 1) & 1) * 32768;
    const bool st = (t + 1 < NT);
    const int ka = (t + 1) * 64;
    // ---- phase 1: quadrant (qm0, qn0) ----
#pragma unroll
    for (int m = 0; m < 4; ++m) {
      af[m][0] = *(const bf8*)(L + aRow + m * 1024 + ks0);
      af[m][1] = *(const bf8*)(L + aRow + m * 1024 + ks1);
    }
#pragma unroll
    for (int n = 0; n < 2; ++n) {
      b0[n][0] = *(const bf8*)(L + bRow + n * 1024 + ks0);
      b0[n][1] = *(const bf8*)(L + bRow + n * 1024 + ks1);
    }
    if (st) { gload16(gA[0] + ka, S + dA[0]); gload16(gA[1] + ka, S + dA[1]); VMW(4); }
    else VMW(2);
    SBAR; LGKM0; SCHED0;
    __builtin_amdgcn_s_setprio(1);
#pragma unroll
    for (int n = 0; n < 2; ++n)
#pragma unroll
      for (int m = 0; m < 4; ++m) { MFMA16(acc[m][n], af[m][0], b0[n][0]); MFMA16(acc[m][n], af[m][1], b0[n][1]); }
    __builtin_amdgcn_s_setprio(0);
    SBAR;
    // ---- phase 2: (qm0, qn1) ----
#pragma unroll
    for (int n = 0; n < 2; ++n) {
      b1[n][0] = *(const bf8*)(L + bRow + (2 + n) * 1024 + ks0);
      b1[n][1] = *(const bf8*)(L + bRow + (2 + n) * 1024 + ks1);
    }
    if (st) { gload16(gB[0] + ka, S + dB[0]); gload16(gB[1] + ka, S + dB[1]); VMW(4); }
    else VMW(0);
    SBAR; LGKM0; SCHED0;
    __builtin_amdgcn_s_setprio(1);
#pragma unroll
    for (int n = 0; n < 2; ++n)
#pragma unroll
      for (int m = 0; m < 4; ++m) { MFMA16(acc[m][2 + n], af[m][0], b1[n][0]); MFMA16(acc[m][2 + n], af[m][1], b1[n][1]); }
    __builtin_amdgcn_s_setprio(0);
    SBAR;
    // ---- phase 3: (qm1, qn1) ----
#pragma unroll
    for (int m = 0; m < 4; ++m) {
      af[m][0] = *(const bf8*)(L + aRow + (4 + m) * 1024 + ks0);
      af[m][1] = *(const bf8*)(L + aRow + (4 + m) * 1024 + ks1);
    }
    if (st) { gload16(gB[2] + ka, S + dB[2]); gload16(gB[3] + ka, S + dB[3]); VMW(4); }
    SBAR; LGKM0; SCHED0;
    __builtin_amdgcn_s_setprio(1);
#pragma unroll
    for (int n = 0; n < 2; ++n)
#pragma unroll
      for (int m = 0; m < 4; ++m) { MFMA16(acc[4 + m][2 + n], af[m][0], b1[n][0]); MFMA16(acc[4 + m][2 + n], af[m][1], b1[n][1]); }
    __builtin_amdgcn_s_setprio(0);
    SBAR;
    // ---- phase 4: (qm1, qn0) ----
    if (st) { gload16(gA[2] + ka, S + dA[2]); gload16(gA[3] + ka, S + dA[3]); VMW(4); }
    SBAR; LGKM0; SCHED0;
    __builtin_amdgcn_s_setprio(1);
#pragma unroll
    for (int n = 0; n < 2; ++n)
#pragma unroll
      for (int m = 0; m < 4; ++m) { MFMA16(acc[4 + m][n], af[m][0], b0[n][0]); MFMA16(acc[4 + m][n], af[m][1], b0[n][1]); }
    __builtin_amdgcn_s_setprio(0);
    SBAR;
  }

  // epilogue: bias + gate/up pair (shfl) + activation + rw scale, bf16 store
  float gbv[4];
#pragma unroll
  for (int n = 0; n < 4; ++n)
    gbv[n] = gbias[(size_t)e * F_DIM + n0 + wn * 64 + n * 16 + lr];
#pragma unroll
  for (int m = 0; m < 8; ++m) {
#pragma unroll
    for (int r = 0; r < 4; ++r) {
      int row = wm * 128 + m * 16 + qq * 4 + r;
      float rwv = rw[(size_t)(t0 + row) * E_DIM + e];
#pragma unroll
      for (int n = 0; n < 4; ++n) {
        float v = acc[m][n][r] + gbv[n];
        float o = __shfl_xor(v, 1, 64);
        float gate = (l & 1) ? o : v;
        float up   = (l & 1) ? v : o;
        gate = fminf(gate, LIMIT_C);
        up   = fminf(fmaxf(up, -LIMIT_C), LIMIT_C);
        float glu = gate / (1.f + __expf(-gate * ALPHA_C));
        float a = (up + 1.f) * glu * rwv;
        if (!(l & 1)) {
          int col = wn * 64 + n * 16 + lr;
          act2[(size_t)(t0 + row) * K2_DIM + e * I_DIM + ((n0 + col) >> 1)] = f2bf(a);
        }
      }
    }
  }
}

// ============ GEMM2: 256x256 tile, BK=64, split-K=4, atomic epilogue ============
// act2(T,8192) x dp_bf(E,H,I)^T(blockwise) -> out(T,H) += routed bias (bias_init)

__global__ __launch_bounds__(512, 2) void gemm2_8(
    const u16* __restrict__ A,      // act2 (T, 8192)
    const u16* __restrict__ dp,     // dp_bf (E,H,I)
    float* __restrict__ out)        // (T,H)
{
  __shared__ __align__(16) u16 ldsbuf[65536];
  const int s  = blockIdx.z;          // split 0..3, K range [s*2048, s*2048+2048)
  const int t0 = blockIdx.y * 256;
  const int n0 = blockIdx.x * 256;    // h
  const int tid = threadIdx.x;
  const int l = tid & 63, w = tid >> 6;
  const int wm = w >> 2, wn = w & 3;

  const int g = tid >> 3, cl = tid & 7;
  int ra[4] = { g, 128 + g, 64 + g, 192 + g };
  int rbb = (g & 31) + ((g >> 5) << 6);
  int rb[4] = { rbb, 128 + rbb, 32 + rbb, 160 + rbb };
  const u16* gA[4]; size_t rpB[4]; int dA[4], dB[4];
#pragma unroll
  for (int j = 0; j < 4; ++j) {
    gA[j] = A + (size_t)(t0 + ra[j]) * K2_DIM + s * 2048 + (cl ^ ((ra[j] >> 1) & 7)) * 8;
    dA[j] = ra[j] * 64 + cl * 8;
    rpB[j] = (size_t)(n0 + rb[j]) * I_DIM + (cl ^ ((rb[j] >> 1) & 7)) * 8;
    dB[j] = 16384 + rb[j] * 64 + cl * 8;
  }

  const int lr = l & 15, qq = l >> 4, sw = (l >> 1) & 7;
  const int ks0 = (qq ^ sw) * 8, ks1 = ((4 + qq) ^ sw) * 8;
  const int aRow = (wm * 128 + lr) * 64;
  const int bRow = 16384 + (wn * 64 + lr) * 64;

  f4 acc[8][4];
#pragma unroll
  for (int i = 0; i < 8; ++i)
#pragma unroll
    for (int j = 0; j < 4; ++j) acc[i][j] = f4{0.f, 0.f, 0.f, 0.f};

  // prologue: tile 0
  {
    const u16* bT = dp + (size_t)(s * 2) * (H_DIM * I_DIM);   // eb = s*2, ki = 0
    gload16(gA[0], ldsbuf + dA[0]); gload16(gA[1], ldsbuf + dA[1]);
    gload16(bT + rpB[0], ldsbuf + dB[0]); gload16(bT + rpB[1], ldsbuf + dB[1]);
    gload16(bT + rpB[2], ldsbuf + dB[2]); gload16(bT + rpB[3], ldsbuf + dB[3]);
    gload16(gA[2], ldsbuf + dA[2]); gload16(gA[3], ldsbuf + dA[3]);
  }
  VMW(4);
  SBAR;

  bf8 af[4][2], b0[2][2], b1[2][2];
  const int NT = 2048 / 64;   // 32
  for (int t = 0; t < NT; ++t) {
    const u16* L = ldsbuf + (t & 1) * 32768;
    u16* S = ldsbuf + ((t + 1) & 1) * 32768;
    const bool st = (t + 1 < NT);
    const int ka = (t + 1) * 64;
    const int kk = s * 2048 + ka;
    const u16* bT = dp + (size_t)(kk >> 10) * (H_DIM * I_DIM) + (kk & 1023);
    // ---- phase 1 ----
#pragma unroll
    for (int m = 0; m < 4; ++m) {
      af[m][0] = *(const bf8*)(L + aRow + m * 1024 + ks0);
      af[m][1] = *(const bf8*)(L + aRow + m * 1024 + ks1);
    }
#pragma unroll
    for (int n = 0; n < 2; ++n) {
      b0[n][0] = *(const bf8*)(L + bRow + n * 1024 + ks0);
      b0[n][1] = *(const bf8*)(L + bRow + n * 1024 + ks1);
    }
    if (st) { gload16(gA[0] + ka, S + dA[0]); gload16(gA[1] + ka, S + dA[1]); VMW(4); }
    else VMW(2);
    SBAR; LGKM0; SCHED0;
    __builtin_amdgcn_s_setprio(1);
#pragma unroll
    for (int n = 0; n < 2; ++n)
#pragma unroll
      for (int m = 0; m < 4; ++m) { MFMA16(acc[m][n], af[m][0], b0[n][0]); MFMA16(acc[m][n], af[m][1], b0[n][1]); }
    __builtin_amdgcn_s_setprio(0);
    SBAR;
    // ---- phase 2 ----
#pragma unroll
    for (int n = 0; n < 2; ++n) {
      b1[n][0] = *(const bf8*)(L + bRow + (2 + n) * 1024 + ks0);
      b1[n][1] = *(const bf8*)(L + bRow + (2 + n) * 1024 + ks1);
    }
    if (st) { gload16(bT + rpB[0], S + dB[0]); gload16(bT + rpB[1], S + dB[1]); VMW(4); }
    else VMW(0);
    SBAR; LGKM0; SCHED0;
    __builtin_amdgcn_s_setprio(1);
#pragma unroll
    for (int n = 0; n < 2; ++n)
#pragma unroll
      for (int m = 0; m < 4; ++m) { MFMA16(acc[m][2 + n], af[m][0], b1[n][0]); MFMA16(acc[m][2 + n], af[m][1], b1[n][1]); }
    __builtin_amdgcn_s_setprio(0);
    SBAR;
    // ---- phase 3 ----
#pragma unroll
    for (int m = 0; m < 4; ++m) {
      af[m][0] = *(const bf8*)(L + aRow + (4 + m) * 1024 + ks0);
      af[m][1] = *(const bf8*)(L + aRow + (4 + m) * 1024 + ks1);
    }
    if (st) { gload16(bT + rpB[2], S + dB[2]); gload16(bT + rpB[3], S + dB[3]); VMW(4); }
    SBAR; LGKM0; SCHED0;
    __builtin_amdgcn_s_setprio(1);
#pragma unroll
    for (int n = 0; n < 2; ++n)
#pragma unroll
      for (int m = 0; m < 4; ++m) { MFMA16(acc[4 + m][2 + n], af[m][0], b1[n][0]); MFMA16(acc[4 + m][2 + n], af[m][1], b1[n][1]); }
    __builtin_amdgcn_s_setprio(0);
    SBAR;
    // ---- phase 4 ----
    if (st) { gload16(gA[2] + ka, S + dA[2]); gload16(gA[3] + ka, S + dA[3]); VMW(4); }
    SBAR; LGKM0; SCHED0;
    __builtin_amdgcn_s_setprio(1);
#pragma unroll
    for (int n = 0; n < 2; ++n)
#pragma unroll
      for (int m = 0; m < 4; ++m) { MFMA16(acc[4 + m][n], af[m][0], b0[n][0]); MFMA16(acc[4 + m][n], af[m][1], b0[n][1]); }
    __builtin_amdgcn_s_setprio(0);
    SBAR;
  }

#pragma unroll
  for (int m = 0; m < 8; ++m)
#pragma unroll
    for (int r = 0; r < 4; ++r) {
      int row = wm * 128 + m * 16 + qq * 4 + r;
#pragma unroll
      for (int n = 0; n < 4; ++n) {
        int col = wn * 64 + n * 16 + lr;
        atomicAdd(out + (size_t)(t0 + row) * H_DIM + n0 + col, acc[m][n][r]);
      }
    }
}

// ---------------- launch ----------------

extern "C" void kernel_launch(void* const* d_in, const int* in_sizes, int n_in,
                              void* d_out, int out_size, void* d_ws, size_t ws_size,
                              hipStream_t stream) {
  const float* hs  = (const float*)d_in[0];
  const float* rw  = (const float*)d_in[1];
  const float* gup = (const float*)d_in[2];
  const float* gub = (const float*)d_in[3];
  const float* dp  = (const float*)d_in[4];
  const float* db  = (const float*)d_in[5];
  float* out = (float*)d_out;
  char* ws = (char*)d_ws;

  u16* hs_bf = (u16*)(ws);                          //  8 MiB (T*H*2)
  u16* gupT  = (u16*)(ws + 8ll  * 1024 * 1024);     // 32 MiB (E*F*H*2)
  u16* dp_bf = (u16*)(ws + 40ll * 1024 * 1024);     // 16 MiB (E*H*I*2)
  u16* act2  = (u16*)(ws + 56ll * 1024 * 1024);     // 64 MiB (T*E*I*2)

  cast_bf16_kernel<<<2048, 256, 0, stream>>>(hs, hs_bf, T_DIM * H_DIM / 4);
  cast_transpose_gup<<<dim3(F_DIM / 32, H_DIM / 32, E_DIM), 256, 0, stream>>>(gup, gupT);
  cast_bf16_kernel<<<2048, 256, 0, stream>>>(dp, dp_bf, E_DIM * H_DIM * I_DIM / 4);
  bias_init<<<T_DIM, 256, 0, stream>>>(rw, db, out);
  gemm1_act8<<<dim3(F_DIM / 256, T_DIM / 256, E_DIM), 512, 0, stream>>>(hs_bf, gupT, rw, gub, act2);
  gemm2_8<<<dim3(H_DIM / 256, T_DIM / 256, 4), 512, 0, stream>>>(act2, dp_bf, out);
}